// Round 4
// baseline (351.227 us; speedup 1.0000x reference)
//
#include <hip/hip_runtime.h>

#define BLOCK  256
#define UNROLL 4
#define CHUNK  (BLOCK * UNROLL)   // elements per block

// clang native vector: valid for __builtin_nontemporal_load, same layout as float4
typedef float f4 __attribute__((ext_vector_type(4)));

// Per-point GICP mahalanobis: maha = res^T * adj(RCR) * res / det(RCR)
// RCR = C_tar[idx] + T3 * C_src * T3^T  (3x3 symmetric SPD)
__global__ __launch_bounds__(BLOCK, 4) void gicp_maha_kernel(
    const float* __restrict__ T,
    const f4*    __restrict__ src,
    const f4*    __restrict__ tar,
    const f4*    __restrict__ cs,
    const f4*    __restrict__ ct,
    const int*   __restrict__ idx,
    float*       __restrict__ partial,  // [gridDim.x], each written once
    int n)
{
    // wave-uniform -> scalar registers
    const float t00 = T[0],  t01 = T[1],  t02 = T[2];
    const float t10 = T[4],  t11 = T[5],  t12 = T[6];
    const float t20 = T[8],  t21 = T[9],  t22 = T[10];
    const float t30 = T[12], t31 = T[13], t32 = T[14];

    const int base = blockIdx.x * CHUNK + threadIdx.x;

    bool valid[UNROLL];
    int  ii[UNROLL];
    int  jj[UNROLL];
    f4   sv[UNROLL];
    f4   c0v[UNROLL], c1v[UNROLL], c2v[UNROLL];
    f4   tpv[UNROLL];
    f4   d0v[UNROLL], d1v[UNROLL], d2v[UNROLL];

    // Phase 1: issue all streaming loads (idx first: gathers depend on it).
    // Non-temporal: read-once data, keep L3 for the gather targets.
    #pragma unroll
    for (int k = 0; k < UNROLL; ++k) {
        int i = base + k * BLOCK;
        valid[k] = (i < n);
        ii[k] = valid[k] ? i : 0;
        jj[k] = __builtin_nontemporal_load(idx + ii[k]);
    }
    #pragma unroll
    for (int k = 0; k < UNROLL; ++k)
        sv[k] = __builtin_nontemporal_load(src + ii[k]);
    #pragma unroll
    for (int k = 0; k < UNROLL; ++k) {
        const size_t bi = (size_t)ii[k] * 4;
        c0v[k] = __builtin_nontemporal_load(cs + bi + 0);
        c1v[k] = __builtin_nontemporal_load(cs + bi + 1);
        c2v[k] = __builtin_nontemporal_load(cs + bi + 2);
    }

    // Phase 2: all gathers (4 independent chains in flight).
    #pragma unroll
    for (int k = 0; k < UNROLL; ++k) {
        const int j = jj[k];
        const size_t bj = (size_t)j * 4;
        tpv[k] = tar[j];
        d0v[k] = ct[bj + 0];
        d1v[k] = ct[bj + 1];
        d2v[k] = ct[bj + 2];
    }

    // Phase 3: compute.
    float local = 0.0f;
    #pragma unroll
    for (int k = 0; k < UNROLL; ++k) {
        const f4 s  = sv[k];
        const f4 tp = tpv[k];

        const float ts0 = s.x * t00 + s.y * t10 + s.z * t20 + s.w * t30;
        const float ts1 = s.x * t01 + s.y * t11 + s.z * t21 + s.w * t31;
        const float ts2 = s.x * t02 + s.y * t12 + s.z * t22 + s.w * t32;
        const float r0 = tp.x - ts0;
        const float r1 = tp.y - ts1;
        const float r2 = tp.z - ts2;

        const f4 c0 = c0v[k], c1 = c1v[k], c2 = c2v[k];

        // U = T3 * C
        const float u00 = t00*c0.x + t01*c1.x + t02*c2.x;
        const float u01 = t00*c0.y + t01*c1.y + t02*c2.y;
        const float u02 = t00*c0.z + t01*c1.z + t02*c2.z;
        const float u10 = t10*c0.x + t11*c1.x + t12*c2.x;
        const float u11 = t10*c0.y + t11*c1.y + t12*c2.y;
        const float u12 = t10*c0.z + t11*c1.z + t12*c2.z;
        const float u20 = t20*c0.x + t21*c1.x + t22*c2.x;
        const float u21 = t20*c0.y + t21*c1.y + t22*c2.y;
        const float u22 = t20*c0.z + t21*c1.z + t22*c2.z;

        // tcov = U * T3^T (symmetric part)
        const float tc00 = u00*t00 + u01*t01 + u02*t02;
        const float tc01 = u00*t10 + u01*t11 + u02*t12;
        const float tc02 = u00*t20 + u01*t21 + u02*t22;
        const float tc11 = u10*t10 + u11*t11 + u12*t12;
        const float tc12 = u10*t20 + u11*t21 + u12*t22;
        const float tc22 = u20*t20 + u21*t21 + u22*t22;

        const f4 d0 = d0v[k], d1 = d1v[k], d2 = d2v[k];

        const float a = d0.x + tc00;
        const float b = d0.y + tc01;
        const float c = d0.z + tc02;
        const float d = d1.y + tc11;
        const float e = d1.z + tc12;
        const float f = d2.z + tc22;

        const float A00 = d * f - e * e;
        const float A01 = c * e - b * f;
        const float A02 = b * e - c * d;
        const float A11 = a * f - c * c;
        const float A12 = b * c - a * e;
        const float A22 = a * d - b * b;

        const float det = a * A00 + b * A01 + c * A02;

        const float num = r0 * r0 * A00 + r1 * r1 * A11 + r2 * r2 * A22
                        + 2.0f * (r0 * r1 * A01 + r0 * r2 * A02 + r1 * r2 * A12);

        local += valid[k] ? (num / det) : 0.0f;
    }

    // wave-64 reduction, then one LDS slot per wave, one store per block
    for (int off = 32; off > 0; off >>= 1)
        local += __shfl_down(local, off, 64);

    __shared__ float wsum[BLOCK / 64];
    const int wave = threadIdx.x >> 6;
    if ((threadIdx.x & 63) == 0) wsum[wave] = local;
    __syncthreads();
    if (threadIdx.x == 0) {
        float s = wsum[0];
        #pragma unroll
        for (int w = 1; w < BLOCK / 64; ++w) s += wsum[w];
        partial[blockIdx.x] = s;
    }
}

__global__ __launch_bounds__(256) void gicp_finalize_kernel(
    const float* __restrict__ partial, float* __restrict__ out,
    int nblocks, double scale)
{
    double s = 0.0;
    for (int k = threadIdx.x; k < nblocks; k += 256)
        s += (double)partial[k];
    for (int off = 32; off > 0; off >>= 1)
        s += __shfl_down(s, off, 64);
    __shared__ double wsum[4];
    const int wave = threadIdx.x >> 6;
    if ((threadIdx.x & 63) == 0) wsum[wave] = s;
    __syncthreads();
    if (threadIdx.x == 0)
        out[0] = (float)((wsum[0] + wsum[1] + wsum[2] + wsum[3]) * scale);
}

extern "C" void kernel_launch(void* const* d_in, const int* in_sizes, int n_in,
                              void* d_out, int out_size, void* d_ws, size_t ws_size,
                              hipStream_t stream) {
    const float* T   = (const float*)d_in[0];
    const f4*    src = (const f4*)d_in[1];
    const f4*    tar = (const f4*)d_in[2];
    const f4*    cs  = (const f4*)d_in[3];
    const f4*    ct  = (const f4*)d_in[4];
    const int*   idx = (const int*)d_in[5];
    const int n = in_sizes[1] / 4;  // src_points is (N,4)

    const int grid = (n + CHUNK - 1) / CHUNK;   // 1954 for n=2e6
    float* partial = (float*)d_ws;              // grid floats, fully overwritten

    gicp_maha_kernel<<<grid, BLOCK, 0, stream>>>(T, src, tar, cs, ct, idx,
                                                 partial, n);
    gicp_finalize_kernel<<<1, 256, 0, stream>>>(partial, (float*)d_out,
                                                grid, 0.5 / (double)n);
}